// Round 7
// baseline (10787.141 us; speedup 1.0000x reference)
//
#include <hip/hip_runtime.h>
#include <hip/hip_bf16.h>
#include <stdint.h>

#define LL 4096
#define EE 300
#define HH 512
#define G4H 2048
#define TT 11
#define TSTART 9
#define TSTOP 10
#define NEGINF -10000.0f

typedef unsigned long long u64;
typedef short short8 __attribute__((ext_vector_type(8)));
typedef float f32x4 __attribute__((ext_vector_type(4)));

__device__ __forceinline__ float sigf(float x){
    x = fminf(fmaxf(x, -30.f), 30.f);
    return 1.0f / (1.0f + __expf(-x));
}
__device__ __forceinline__ float tanhfast(float x){
    x = fminf(fmaxf(x, -15.f), 15.f);
    float e = __expf(-2.0f * x);
    return (1.0f - e) / (1.0f + e);
}
__device__ __forceinline__ u64 lda(const u64* p){
    return __hip_atomic_load(p, __ATOMIC_RELAXED, __HIP_MEMORY_SCOPE_AGENT);
}
__device__ __forceinline__ unsigned f2bf(float f){   // RNE f32->bf16
    unsigned u = __float_as_uint(f);
    return ((u + 0x7FFFu + ((u >> 16) & 1u)) >> 16) & 0xFFFFu;
}

// ---------------- K0: zero the h-communication buffers (fresh tags each call)
__global__ void k0_zero(u64* __restrict__ comm){
    int i = blockIdx.x * blockDim.x + threadIdx.x;
    if (i < 2 * 2 * HH) comm[i] = 0ull;
}

// ---------------- K1: xg[dir][t][r] = emb[sent[t]] . w_ih[dir][r] + b_ih[r] + b_hh[r]
__global__ __launch_bounds__(256) void k1_xg(
    const int* __restrict__ sent, const float* __restrict__ emb,
    const float* __restrict__ wih_f, const float* __restrict__ bih_f, const float* __restrict__ bhh_f,
    const float* __restrict__ wih_b, const float* __restrict__ bih_b, const float* __restrict__ bhh_b,
    float* __restrict__ xg_f, float* __restrict__ xg_b)
{
    __shared__ float elds[32 * 304];
    int t0  = blockIdx.x * 32;
    int r0  = blockIdx.y * 256;
    int dir = blockIdx.z;
    const float* wih = dir ? wih_b : wih_f;
    const float* bih = dir ? bih_b : bih_f;
    const float* bhh = dir ? bhh_b : bhh_f;
    float* xg = dir ? xg_b : xg_f;

    for (int idx = threadIdx.x; idx < 32 * EE; idx += 256){
        int i = idx / EE, e = idx - i * EE;
        elds[i * 304 + e] = emb[(long)sent[t0 + i] * EE + e];
    }
    __syncthreads();

    int rA = r0 + (threadIdx.x & 127);
    int rB = rA + 128;
    int half = threadIdx.x >> 7;
    float accA[16], accB[16];
    #pragma unroll
    for (int i = 0; i < 16; i++){ accA[i] = 0.f; accB[i] = 0.f; }
    const float* wrowA = wih + (long)rA * EE;
    const float* wrowB = wih + (long)rB * EE;
    for (int e4 = 0; e4 < 75; e4++){
        float4 wa = *reinterpret_cast<const float4*>(wrowA + e4 * 4);
        float4 wb = *reinterpret_cast<const float4*>(wrowB + e4 * 4);
        #pragma unroll
        for (int i = 0; i < 16; i++){
            float4 ev = *reinterpret_cast<const float4*>(&elds[(half * 16 + i) * 304 + e4 * 4]);
            accA[i] += wa.x * ev.x + wa.y * ev.y + wa.z * ev.z + wa.w * ev.w;
            accB[i] += wb.x * ev.x + wb.y * ev.y + wb.z * ev.z + wb.w * ev.w;
        }
    }
    float bA = bih[rA] + bhh[rA];
    float bB = bih[rB] + bhh[rB];
    #pragma unroll
    for (int i = 0; i < 16; i++){
        int t = t0 + half * 16 + i;
        xg[(long)t * G4H + rA] = accA[i] + bA;
        xg[(long)t * G4H + rB] = accB[i] + bB;
    }
}

// ---------------- K2: persistent BiLSTM — role-split waves + MFMA (ILP4).
// 64 blocks x 512 thr. bid>>5 = dir, b = bid&31 owns j [16b,16b+16).
// Waves 0-3 (tid<256): compute — wave v owns j {j0+4v..j0+4v+3}; h replicated
//   across MFMA B-cols puts the 4 gate preacts of j in one lane's acc; 4
//   independent MFMA chains (dep latency ~4 not 16); publish from (l&15)==0.
// Waves 4-7: dedicated pollers — thread u=tid-256 polls words 2u,2u+1 with
//   depth-2 pipelining (sample grain ~RT/2), stages bf16-pair to hb, barrier.
// Divergence is wave-uniform; each wave executes exactly one s_barrier/iter.
__global__ __launch_bounds__(512) void k2_lstm(
    const float* __restrict__ whh_f, const float* __restrict__ whh_b,
    const float* __restrict__ xg_f, const float* __restrict__ xg_b,
    float* __restrict__ hs_f, float* __restrict__ hs_b,
    u64* __restrict__ comm)
{
    int dir = blockIdx.x >> 5;
    int b   = blockIdx.x & 31;
    int j0  = b * 16;
    int tid = threadIdx.x;

    const float* whh = dir ? whh_b : whh_f;
    const float* xg  = dir ? xg_b  : xg_f;
    float* hs        = dir ? hs_b  : hs_f;
    u64* cm          = comm + dir * 2 * HH;

    __shared__ __align__(16) unsigned hb[2][256];   // h as packed bf16 pairs

    if (tid >= 256){
        // ---------------- poller waves ----------------
        int u = tid - 256;
        for (int s = 0; s < LL; ++s){
            if (s > 0){
                u64* pw = cm + (s & 1) * HH + 2 * u;
                unsigned want = (unsigned)s;
                // depth-2 pipelined poll per word, individually retired
                u64 a0 = lda(pw),     b0 = lda(pw + 1);
                u64 a1 = lda(pw),     b1 = lda(pw + 1);
                bool oka = false, okb = false;
                unsigned ra = 0, rb = 0;
                for (;;){
                    if (!oka){
                        if ((unsigned)(a0 >> 32) == want){ ra = (unsigned)a0; oka = true; }
                        else { a0 = a1; a1 = lda(pw); }
                    }
                    if (!okb){
                        if ((unsigned)(b0 >> 32) == want){ rb = (unsigned)b0; okb = true; }
                        else { b0 = b1; b1 = lda(pw + 1); }
                    }
                    if (__all(oka && okb)) break;
                }
                hb[s & 1][u] = f2bf(__uint_as_float(ra))
                             | (f2bf(__uint_as_float(rb)) << 16);
            }
            __syncthreads();
        }
    } else {
        // ---------------- compute waves ----------------
        int v   = tid >> 6;
        int l   = tid & 63;
        int grp = l >> 4;
        int jmine = j0 + v * 4 + grp;

        // A fragments: lane holds A[m=l&15][k=(l>>4)*8+j], m = jloc*4 + gate.
        short8 afrag[16];
        {
            int m    = l & 15;
            int jloc = m >> 2;
            int g    = m & 3;
            const float* wp = whh + (size_t)(g * HH + j0 + v * 4 + jloc) * HH + (l >> 4) * 8;
            #pragma unroll
            for (int kc = 0; kc < 16; kc++){
                float4 w0 = *reinterpret_cast<const float4*>(wp + kc * 32);
                float4 w1 = *reinterpret_cast<const float4*>(wp + kc * 32 + 4);
                union { unsigned u[4]; short8 s; } fr;
                fr.u[0] = f2bf(w0.x) | (f2bf(w0.y) << 16);
                fr.u[1] = f2bf(w0.z) | (f2bf(w0.w) << 16);
                fr.u[2] = f2bf(w1.x) | (f2bf(w1.y) << 16);
                fr.u[3] = f2bf(w1.z) | (f2bf(w1.w) << 16);
                afrag[kc] = fr.s;
            }
        }

        float c = 0.f;
        for (int s = 0; s < LL; ++s){
            int t = dir ? (LL - 1 - s) : s;
            // xg in flight across the barrier wait
            const float* xp = xg + (size_t)t * G4H + jmine;
            float xg0 = xp[0], xg1 = xp[HH], xg2 = xp[2 * HH], xg3 = xp[3 * HH];

            __syncthreads();

            f32x4 ac0 = {0.f,0.f,0.f,0.f}, ac1 = ac0, ac2 = ac0, ac3 = ac0;
            if (s > 0){
                const char* hbase = (const char*)&hb[s & 1][0] + grp * 16;
                #pragma unroll
                for (int kc = 0; kc < 4; kc++){
                    short8 b0 = *reinterpret_cast<const short8*>(hbase + kc * 64);
                    short8 b1 = *reinterpret_cast<const short8*>(hbase + (4 + kc) * 64);
                    short8 b2 = *reinterpret_cast<const short8*>(hbase + (8 + kc) * 64);
                    short8 b3 = *reinterpret_cast<const short8*>(hbase + (12 + kc) * 64);
                    ac0 = __builtin_amdgcn_mfma_f32_16x16x32_bf16(afrag[kc],      b0, ac0, 0, 0, 0);
                    ac1 = __builtin_amdgcn_mfma_f32_16x16x32_bf16(afrag[4 + kc],  b1, ac1, 0, 0, 0);
                    ac2 = __builtin_amdgcn_mfma_f32_16x16x32_bf16(afrag[8 + kc],  b2, ac2, 0, 0, 0);
                    ac3 = __builtin_amdgcn_mfma_f32_16x16x32_bf16(afrag[12 + kc], b3, ac3, 0, 0, 0);
                }
            }

            float vi = ((ac0[0] + ac1[0]) + (ac2[0] + ac3[0])) + xg0;
            float vf = ((ac0[1] + ac1[1]) + (ac2[1] + ac3[1])) + xg1;
            float vgg= ((ac0[2] + ac1[2]) + (ac2[2] + ac3[2])) + xg2;
            float vo = ((ac0[3] + ac1[3]) + (ac2[3] + ac3[3])) + xg3;
            c = sigf(vf) * c + sigf(vi) * tanhfast(vgg);
            float hv = sigf(vo) * tanhfast(c);

            if ((l & 15) == 0){
                union { float f; unsigned u; } cv; cv.f = hv;
                u64 pk = ((u64)(s + 1) << 32) | (u64)cv.u;
                __hip_atomic_store(cm + ((s + 1) & 1) * HH + jmine, pk,
                                   __ATOMIC_RELAXED, __HIP_MEMORY_SCOPE_AGENT);
                hs[(size_t)t * HH + jmine] = hv;
            }
        }
    }
}

// ---------------- K3: feats[t][n] = w_tag[n] . [hf[t], hb[t]] + b_tag[n]
__global__ __launch_bounds__(64) void k3_feats(
    const float* __restrict__ hs_f, const float* __restrict__ hs_b,
    const float* __restrict__ wtag, const float* __restrict__ btag,
    float* __restrict__ feats)
{
    int t = blockIdx.x;
    int lane = threadIdx.x;
    float hreg[16];
    #pragma unroll
    for (int q = 0; q < 16; q++){
        int k = q * 64 + lane;
        hreg[q] = (q < 8) ? hs_f[(long)t * HH + k] : hs_b[(long)t * HH + (k - HH)];
    }
    for (int n = 0; n < TT; n++){
        float a = 0.f;
        #pragma unroll
        for (int q = 0; q < 16; q++){
            a += wtag[n * 1024 + q * 64 + lane] * hreg[q];
        }
        #pragma unroll
        for (int off = 32; off; off >>= 1) a += __shfl_down(a, off, 64);
        if (lane == 0) feats[t * 12 + n] = a + btag[n];
    }
}

// ---------------- K4a: per-chunk max-plus products P_c[n][s] (64 chunks of 64)
__global__ __launch_bounds__(64) void k4a_chunk(
    const float* __restrict__ feats, const float* __restrict__ trans,
    float* __restrict__ Pmat)
{
    int c = blockIdx.x;
    int lane = threadIdx.x;             // lane = start state s (active < TT)
    float tr[TT][TT];
    #pragma unroll
    for (int n = 0; n < TT; n++)
        #pragma unroll
        for (int p = 0; p < TT; p++) tr[n][p] = trans[n * TT + p];

    float pv[TT];
    #pragma unroll
    for (int n = 0; n < TT; n++) pv[n] = (n == lane) ? 0.f : NEGINF;

    for (int i = 0; i < 64; i++){
        int t = c * 64 + i;
        float ft[TT];
        #pragma unroll
        for (int n = 0; n < TT; n++) ft[n] = feats[t * 12 + n];
        float pn[TT];
        #pragma unroll
        for (int n = 0; n < TT; n++){
            float m = tr[n][0] + pv[0];
            #pragma unroll
            for (int p = 1; p < TT; p++) m = fmaxf(m, tr[n][p] + pv[p]);
            pn[n] = m + ft[n];
        }
        #pragma unroll
        for (int n = 0; n < TT; n++) pv[n] = pn[n];
    }
    if (lane < TT){
        #pragma unroll
        for (int n = 0; n < TT; n++) Pmat[(c * TT + n) * TT + lane] = pv[n];
    }
}

// ---------------- K4b: sequential boundary combine (fv before each chunk)
__global__ __launch_bounds__(64) void k4b_bound(
    const float* __restrict__ Pmat, float* __restrict__ fvb)
{
    int lane = threadIdx.x;
    int ln = (lane < TT) ? lane : 0;
    float fv[TT];
    #pragma unroll
    for (int n = 0; n < TT; n++) fv[n] = (n == TSTART) ? 0.f : NEGINF;

    for (int c = 0; c < 64; c++){
        if (lane < TT) fvb[c * TT + lane] = fv[lane];
        float nf = NEGINF;
        #pragma unroll
        for (int s = 0; s < TT; s++)
            nf = fmaxf(nf, Pmat[(c * TT + ln) * TT + s] + fv[s]);
        #pragma unroll
        for (int n = 0; n < TT; n++) fv[n] = __shfl(nf, n, 64);
    }
    if (lane < TT) fvb[64 * TT + lane] = fv[lane];
}

// ---------------- K4c: per-chunk backpointer recompute (nibble-packed u64/step)
__global__ __launch_bounds__(64) void k4c_bp(
    const float* __restrict__ feats, const float* __restrict__ trans,
    const float* __restrict__ fvb, u64* __restrict__ bpw)
{
    int c = blockIdx.x;
    int lane = threadIdx.x;             // lane = next state n (active < TT)
    int ln = (lane < TT) ? lane : 0;
    float trl[TT];
    #pragma unroll
    for (int p = 0; p < TT; p++) trl[p] = trans[ln * TT + p];
    float fv[TT];
    #pragma unroll
    for (int n = 0; n < TT; n++) fv[n] = fvb[c * TT + n];

    for (int i = 0; i < 64; i++){
        int t = c * 64 + i;
        float best = NEGINF; int bp = 0;
        #pragma unroll
        for (int p = 0; p < TT; p++){
            float sp = trl[p] + fv[p];
            if (sp > best){ best = sp; bp = p; }
        }
        if (lane >= TT) bp = 0;
        unsigned lo = (lane < 8) ? ((unsigned)bp << (4 * lane)) : 0u;
        unsigned hi = (lane >= 8 && lane < TT) ? ((unsigned)bp << (4 * (lane - 8))) : 0u;
        #pragma unroll
        for (int off = 1; off < 16; off <<= 1){
            lo |= __shfl_xor(lo, off, 16); hi |= __shfl_xor(hi, off, 16);
        }
        if (lane == 0) bpw[t] = (u64)lo | ((u64)hi << 32);
        float nf = (lane < TT) ? best + feats[t * 12 + ln] : NEGINF;
        #pragma unroll
        for (int n = 0; n < TT; n++) fv[n] = __shfl(nf, n, 64);
    }
}

// ---------------- K4d: terminal + backtrace
__global__ __launch_bounds__(256) void k4d_bt(
    const u64* __restrict__ bpw, const float* __restrict__ fvb,
    const float* __restrict__ trans, float* __restrict__ out)
{
    __shared__ u64 bl[LL];
    int tid = threadIdx.x;
    for (int i = tid; i < LL; i += 256) bl[i] = bpw[i];
    __syncthreads();

    if (tid < 64){
        int lane = tid;
        int ln = (lane < TT) ? lane : 0;
        float term = (lane < TT) ? (fvb[64 * TT + ln] + trans[TSTOP * TT + ln]) : -3.0e38f;
        int idx = (lane < TT) ? lane : 63;
        #pragma unroll
        for (int off = 32; off; off >>= 1){
            float os = __shfl_down(term, off, 64);
            int   oi = __shfl_down(idx,  off, 64);
            if (os > term || (os == term && oi < idx)){ term = os; idx = oi; }
        }
        if (lane == 0){
            out[0] = term;
            int tag = idx;
            out[1 + (LL - 1)] = (float)tag;
            for (int u = LL - 1; u >= 1; --u){
                tag = (int)((bl[u] >> (4 * tag)) & 15ull);
                out[u] = (float)tag;   // out[1 + (u-1)]
            }
        }
    }
}

__global__ void k_dbg(float* out, float v){ out[0] = v; }

extern "C" void kernel_launch(void* const* d_in, const int* in_sizes, int n_in,
                              void* d_out, int out_size, void* d_ws, size_t ws_size,
                              hipStream_t stream)
{
    const int*   sent  = (const int*)  d_in[0];
    const float* emb   = (const float*)d_in[1];
    const float* wih_f = (const float*)d_in[2];
    const float* whh_f = (const float*)d_in[3];
    const float* bih_f = (const float*)d_in[4];
    const float* bhh_f = (const float*)d_in[5];
    const float* wih_b = (const float*)d_in[6];
    const float* whh_b = (const float*)d_in[7];
    const float* bih_b = (const float*)d_in[8];
    const float* bhh_b = (const float*)d_in[9];
    const float* wtag  = (const float*)d_in[10];
    const float* btag  = (const float*)d_in[11];
    const float* trans = (const float*)d_in[12];
    float* out = (float*)d_out;

    char* ws = (char*)d_ws;
    size_t off = 0;
    float* xg_f = (float*)(ws + off); off += (size_t)LL * G4H * 4;
    float* xg_b = (float*)(ws + off); off += (size_t)LL * G4H * 4;
    float* hs_f = (float*)(ws + off); off += (size_t)LL * HH * 4;
    float* hs_b = (float*)(ws + off); off += (size_t)LL * HH * 4;
    float* feats= (float*)(ws + off); off += (size_t)LL * 12 * 4;
    u64* comm   = (u64*)(ws + off);   off += 2 * 2 * HH * 8;
    float* Pmat = (float*)(ws + off); off += (size_t)64 * TT * TT * 4;
    float* fvb  = (float*)(ws + off); off += (size_t)65 * TT * 4 + 64;
    u64* bpw    = (u64*)(ws + off);   off += (size_t)LL * 8;

    if (off > ws_size){
        k_dbg<<<1, 1, 0, stream>>>(out, (float)ws_size);
        return;
    }

    k0_zero<<<8, 256, 0, stream>>>(comm);
    k1_xg<<<dim3(128, 8, 2), 256, 0, stream>>>(sent, emb, wih_f, bih_f, bhh_f,
                                               wih_b, bih_b, bhh_b, xg_f, xg_b);
    k2_lstm<<<64, 512, 0, stream>>>(whh_f, whh_b, xg_f, xg_b, hs_f, hs_b, comm);
    k3_feats<<<LL, 64, 0, stream>>>(hs_f, hs_b, wtag, btag, feats);
    k4a_chunk<<<64, 64, 0, stream>>>(feats, trans, Pmat);
    k4b_bound<<<1, 64, 0, stream>>>(Pmat, fvb);
    k4c_bp<<<64, 64, 0, stream>>>(feats, trans, fvb, bpw);
    k4d_bt<<<1, 256, 0, stream>>>(bpw, fvb, trans, out);
}

// Round 9
// 6632.536 us; speedup vs baseline: 1.6264x; 1.6264x over previous
//
#include <hip/hip_runtime.h>
#include <hip/hip_bf16.h>
#include <hip/hip_fp16.h>
#include <stdint.h>

#define LL 4096
#define EE 300
#define HH 512
#define G4H 2048
#define TT 11
#define TSTART 9
#define TSTOP 10
#define NEGINF -10000.0f

typedef unsigned long long u64;
typedef _Float16 h2v __attribute__((ext_vector_type(2)));

__device__ __forceinline__ float sigf(float x){
    x = fminf(fmaxf(x, -30.f), 30.f);
    return 1.0f / (1.0f + __expf(-x));
}
__device__ __forceinline__ float tanhfast(float x){
    x = fminf(fmaxf(x, -15.f), 15.f);
    float e = __expf(-2.0f * x);
    return (1.0f - e) / (1.0f + e);
}
__device__ __forceinline__ u64 lda(const u64* p){
    return __hip_atomic_load(p, __ATOMIC_RELAXED, __HIP_MEMORY_SCOPE_AGENT);
}
__device__ __forceinline__ h2v u2h(unsigned u){
    union { unsigned v; h2v h; } c; c.v = u; return c.h;
}
__device__ __forceinline__ h2v pk(float a, float b){
    auto r = __builtin_amdgcn_cvt_pkrtz(a, b);      // __fp16 ext_vector(2)
    union { decltype(r) x; h2v h; } c; c.x = r; return c.h;
}

// ---------------- K0: zero the h-communication buffers (fresh tags each call)
__global__ void k0_zero(u64* __restrict__ comm){
    int i = blockIdx.x * blockDim.x + threadIdx.x;
    if (i < 2 * 2 * HH) comm[i] = 0ull;
}

// ---------------- K1: xg[dir][t][r] = emb[sent[t]] . w_ih[dir][r] + b_ih[r] + b_hh[r]
__global__ __launch_bounds__(256) void k1_xg(
    const int* __restrict__ sent, const float* __restrict__ emb,
    const float* __restrict__ wih_f, const float* __restrict__ bih_f, const float* __restrict__ bhh_f,
    const float* __restrict__ wih_b, const float* __restrict__ bih_b, const float* __restrict__ bhh_b,
    float* __restrict__ xg_f, float* __restrict__ xg_b)
{
    __shared__ float elds[32 * 304];
    int t0  = blockIdx.x * 32;
    int r0  = blockIdx.y * 256;
    int dir = blockIdx.z;
    const float* wih = dir ? wih_b : wih_f;
    const float* bih = dir ? bih_b : bih_f;
    const float* bhh = dir ? bhh_b : bhh_f;
    float* xg = dir ? xg_b : xg_f;

    for (int idx = threadIdx.x; idx < 32 * EE; idx += 256){
        int i = idx / EE, e = idx - i * EE;
        elds[i * 304 + e] = emb[(long)sent[t0 + i] * EE + e];
    }
    __syncthreads();

    int rA = r0 + (threadIdx.x & 127);
    int rB = rA + 128;
    int half = threadIdx.x >> 7;
    float accA[16], accB[16];
    #pragma unroll
    for (int i = 0; i < 16; i++){ accA[i] = 0.f; accB[i] = 0.f; }
    const float* wrowA = wih + (long)rA * EE;
    const float* wrowB = wih + (long)rB * EE;
    for (int e4 = 0; e4 < 75; e4++){
        float4 wa = *reinterpret_cast<const float4*>(wrowA + e4 * 4);
        float4 wb = *reinterpret_cast<const float4*>(wrowB + e4 * 4);
        #pragma unroll
        for (int i = 0; i < 16; i++){
            float4 ev = *reinterpret_cast<const float4*>(&elds[(half * 16 + i) * 304 + e4 * 4]);
            accA[i] += wa.x * ev.x + wa.y * ev.y + wa.z * ev.z + wa.w * ev.w;
            accB[i] += wb.x * ev.x + wb.y * ev.y + wb.z * ev.z + wb.w * ev.w;
        }
    }
    float bA = bih[rA] + bhh[rA];
    float bB = bih[rB] + bhh[rB];
    #pragma unroll
    for (int i = 0; i < 16; i++){
        int t = t0 + half * 16 + i;
        xg[(long)t * G4H + rA] = accA[i] + bA;
        xg[(long)t * G4H + rB] = accB[i] + bB;
    }
}

// ---------------- K2: persistent BiLSTM — R1 structure, f16 staging + dot2.
// 64 blocks x 512 thr. bid>>5 = dir, b = bid&31 owns j [16b,16b+16).
// Thread (w=tid>>6, l=tid&63) owns row g*HH+j0+jl (g=l>>4, jl=l&15) over cols
// [w*64, w*64+64). Per step: thread tid polls comm word tid (one word each),
// stages h as f16 to LDS, barrier; dot via 8 wave-uniform b128 reads + 32
// v_dot2_f32_f16 (4 independent acc chains); plds partial, barrier; wave0
// reduces 8 partials + gates + publishes (lanes 0-15). Exactly R1 otherwise.
__global__ __launch_bounds__(512) void k2_lstm(
    const float* __restrict__ whh_f, const float* __restrict__ whh_b,
    const float* __restrict__ xg_f, const float* __restrict__ xg_b,
    float* __restrict__ hs_f, float* __restrict__ hs_b,
    u64* __restrict__ comm)
{
    int dir = blockIdx.x >> 5;
    int b   = blockIdx.x & 31;
    int j0  = b * 16;
    int tid = threadIdx.x;
    int w   = tid >> 6;
    int l   = tid & 63;
    int g   = l >> 4;
    int jl  = l & 15;
    int row = g * HH + j0 + jl;

    const float* whh = dir ? whh_b : whh_f;
    const float* xg  = dir ? xg_b  : xg_f;
    float* hs        = dir ? hs_b  : hs_f;
    u64* cm          = comm + dir * 2 * HH;

    // weights for my row, cols [w*64, w*64+64), packed f16 pairs
    h2v wreg[32];
    {
        const float* wp = whh + (size_t)row * HH + w * 64;
        #pragma unroll
        for (int m = 0; m < 32; m += 2){
            float4 v = *reinterpret_cast<const float4*>(wp + 2 * m);
            wreg[m]     = pk(v.x, v.y);
            wreg[m + 1] = pk(v.z, v.w);
        }
    }

    __shared__ __align__(16) unsigned short hl16[2][HH];
    __shared__ float plds[2][512];
    float c = 0.f;

    for (int s = 0; s < LL; ++s){
        int t = dir ? (LL - 1 - s) : s;
        // xg prefetch for the tail (wave0 rows only); in flight during poll
        float xgv = 0.f;
        if (tid < 64) xgv = xg[(size_t)t * G4H + row];

        if (s == 0){
            hl16[0][tid] = 0;
        } else {
            const u64* pw = cm + (s & 1) * HH + tid;
            u64 v = lda(pw);
            unsigned want = (unsigned)s;
            while (!__all((unsigned)(v >> 32) == want)){
                if ((unsigned)(v >> 32) != want) v = lda(pw);
            }
            float hval = __uint_as_float((unsigned)v);
            union { h2v h; unsigned u; } cv2; cv2.h = pk(hval, hval);
            hl16[s & 1][tid] = (unsigned short)(cv2.u & 0xFFFFu);
        }
        __syncthreads();

        // dot over my 64-col slice (wave-uniform broadcast b128 reads)
        float a0 = 0.f, a1 = 0.f, a2 = 0.f, a3 = 0.f;
        {
            const uint4* hseg = reinterpret_cast<const uint4*>(&hl16[s & 1][w * 64]);
            #pragma unroll
            for (int q = 0; q < 8; q += 2){
                uint4 h0 = hseg[q];
                uint4 h1 = hseg[q + 1];
                a0 = __builtin_amdgcn_fdot2(wreg[4*q+0], u2h(h0.x), a0, false);
                a1 = __builtin_amdgcn_fdot2(wreg[4*q+1], u2h(h0.y), a1, false);
                a2 = __builtin_amdgcn_fdot2(wreg[4*q+2], u2h(h0.z), a2, false);
                a3 = __builtin_amdgcn_fdot2(wreg[4*q+3], u2h(h0.w), a3, false);
                a0 = __builtin_amdgcn_fdot2(wreg[4*q+4], u2h(h1.x), a0, false);
                a1 = __builtin_amdgcn_fdot2(wreg[4*q+5], u2h(h1.y), a1, false);
                a2 = __builtin_amdgcn_fdot2(wreg[4*q+6], u2h(h1.z), a2, false);
                a3 = __builtin_amdgcn_fdot2(wreg[4*q+7], u2h(h1.w), a3, false);
            }
        }
        plds[s & 1][tid] = (a0 + a1) + (a2 + a3);
        __syncthreads();

        if (w == 0){
            float sum = 0.f;
            #pragma unroll
            for (int q = 0; q < 8; q++) sum += plds[s & 1][q * 64 + l];
            float pre = sum + xgv;
            float vi = __shfl(pre, jl,      64);
            float vf = __shfl(pre, 16 + jl, 64);
            float vg = __shfl(pre, 32 + jl, 64);
            float vo = __shfl(pre, 48 + jl, 64);
            c = sigf(vf) * c + sigf(vi) * tanhfast(vg);
            float h = sigf(vo) * tanhfast(c);
            if (l < 16){
                union { float f; unsigned u; } hv; hv.f = h;
                u64 pk2 = ((u64)(s + 1) << 32) | (u64)hv.u;
                __hip_atomic_store(cm + ((s + 1) & 1) * HH + (j0 + l), pk2,
                                   __ATOMIC_RELAXED, __HIP_MEMORY_SCOPE_AGENT);
                hs[(size_t)t * HH + (j0 + l)] = h;
            }
        }
        // waves 1-7 run ahead to the next poll; plds/hl16 are parity
        // double-buffered, and no wave reaches parity reuse (s+2) before
        // wave0 passes barrier(s+1), which requires it read plds[s&1].
    }
}

// ---------------- K3: feats[t][n] = w_tag[n] . [hf[t], hb[t]] + b_tag[n]
__global__ __launch_bounds__(64) void k3_feats(
    const float* __restrict__ hs_f, const float* __restrict__ hs_b,
    const float* __restrict__ wtag, const float* __restrict__ btag,
    float* __restrict__ feats)
{
    int t = blockIdx.x;
    int lane = threadIdx.x;
    float hreg[16];
    #pragma unroll
    for (int q = 0; q < 16; q++){
        int k = q * 64 + lane;
        hreg[q] = (q < 8) ? hs_f[(long)t * HH + k] : hs_b[(long)t * HH + (k - HH)];
    }
    for (int n = 0; n < TT; n++){
        float a = 0.f;
        #pragma unroll
        for (int q = 0; q < 16; q++){
            a += wtag[n * 1024 + q * 64 + lane] * hreg[q];
        }
        #pragma unroll
        for (int off = 32; off; off >>= 1) a += __shfl_down(a, off, 64);
        if (lane == 0) feats[t * 12 + n] = a + btag[n];
    }
}

// ---------------- K4a: per-chunk max-plus products P_c[n][s] (64 chunks of 64)
__global__ __launch_bounds__(64) void k4a_chunk(
    const float* __restrict__ feats, const float* __restrict__ trans,
    float* __restrict__ Pmat)
{
    int c = blockIdx.x;
    int lane = threadIdx.x;             // lane = start state s (active < TT)
    float tr[TT][TT];
    #pragma unroll
    for (int n = 0; n < TT; n++)
        #pragma unroll
        for (int p = 0; p < TT; p++) tr[n][p] = trans[n * TT + p];

    float pv[TT];
    #pragma unroll
    for (int n = 0; n < TT; n++) pv[n] = (n == lane) ? 0.f : NEGINF;

    for (int i = 0; i < 64; i++){
        int t = c * 64 + i;
        float ft[TT];
        #pragma unroll
        for (int n = 0; n < TT; n++) ft[n] = feats[t * 12 + n];
        float pn[TT];
        #pragma unroll
        for (int n = 0; n < TT; n++){
            float m = tr[n][0] + pv[0];
            #pragma unroll
            for (int p = 1; p < TT; p++) m = fmaxf(m, tr[n][p] + pv[p]);
            pn[n] = m + ft[n];
        }
        #pragma unroll
        for (int n = 0; n < TT; n++) pv[n] = pn[n];
    }
    if (lane < TT){
        #pragma unroll
        for (int n = 0; n < TT; n++) Pmat[(c * TT + n) * TT + lane] = pv[n];
    }
}

// ---------------- K4b: sequential boundary combine (fv before each chunk)
__global__ __launch_bounds__(64) void k4b_bound(
    const float* __restrict__ Pmat, float* __restrict__ fvb)
{
    int lane = threadIdx.x;
    int ln = (lane < TT) ? lane : 0;
    float fv[TT];
    #pragma unroll
    for (int n = 0; n < TT; n++) fv[n] = (n == TSTART) ? 0.f : NEGINF;

    for (int c = 0; c < 64; c++){
        if (lane < TT) fvb[c * TT + lane] = fv[lane];
        float nf = NEGINF;
        #pragma unroll
        for (int s = 0; s < TT; s++)
            nf = fmaxf(nf, Pmat[(c * TT + ln) * TT + s] + fv[s]);
        #pragma unroll
        for (int n = 0; n < TT; n++) fv[n] = __shfl(nf, n, 64);
    }
    if (lane < TT) fvb[64 * TT + lane] = fv[lane];
}

// ---------------- K4c: per-chunk backpointer recompute (nibble-packed u64/step)
__global__ __launch_bounds__(64) void k4c_bp(
    const float* __restrict__ feats, const float* __restrict__ trans,
    const float* __restrict__ fvb, u64* __restrict__ bpw)
{
    int c = blockIdx.x;
    int lane = threadIdx.x;             // lane = next state n (active < TT)
    int ln = (lane < TT) ? lane : 0;
    float trl[TT];
    #pragma unroll
    for (int p = 0; p < TT; p++) trl[p] = trans[ln * TT + p];
    float fv[TT];
    #pragma unroll
    for (int n = 0; n < TT; n++) fv[n] = fvb[c * TT + n];

    for (int i = 0; i < 64; i++){
        int t = c * 64 + i;
        float best = NEGINF; int bp = 0;
        #pragma unroll
        for (int p = 0; p < TT; p++){
            float sp = trl[p] + fv[p];
            if (sp > best){ best = sp; bp = p; }
        }
        if (lane >= TT) bp = 0;
        unsigned lo = (lane < 8) ? ((unsigned)bp << (4 * lane)) : 0u;
        unsigned hi = (lane >= 8 && lane < TT) ? ((unsigned)bp << (4 * (lane - 8))) : 0u;
        #pragma unroll
        for (int off = 1; off < 16; off <<= 1){
            lo |= __shfl_xor(lo, off, 16); hi |= __shfl_xor(hi, off, 16);
        }
        if (lane == 0) bpw[t] = (u64)lo | ((u64)hi << 32);
        float nf = (lane < TT) ? best + feats[t * 12 + ln] : NEGINF;
        #pragma unroll
        for (int n = 0; n < TT; n++) fv[n] = __shfl(nf, n, 64);
    }
}

// ---------------- K4d: terminal + backtrace
__global__ __launch_bounds__(256) void k4d_bt(
    const u64* __restrict__ bpw, const float* __restrict__ fvb,
    const float* __restrict__ trans, float* __restrict__ out)
{
    __shared__ u64 bl[LL];
    int tid = threadIdx.x;
    for (int i = tid; i < LL; i += 256) bl[i] = bpw[i];
    __syncthreads();

    if (tid < 64){
        int lane = tid;
        int ln = (lane < TT) ? lane : 0;
        float term = (lane < TT) ? (fvb[64 * TT + ln] + trans[TSTOP * TT + ln]) : -3.0e38f;
        int idx = (lane < TT) ? lane : 63;
        #pragma unroll
        for (int off = 32; off; off >>= 1){
            float os = __shfl_down(term, off, 64);
            int   oi = __shfl_down(idx,  off, 64);
            if (os > term || (os == term && oi < idx)){ term = os; idx = oi; }
        }
        if (lane == 0){
            out[0] = term;
            int tag = idx;
            out[1 + (LL - 1)] = (float)tag;
            for (int u = LL - 1; u >= 1; --u){
                tag = (int)((bl[u] >> (4 * tag)) & 15ull);
                out[u] = (float)tag;   // out[1 + (u-1)]
            }
        }
    }
}

__global__ void k_dbg(float* out, float v){ out[0] = v; }

extern "C" void kernel_launch(void* const* d_in, const int* in_sizes, int n_in,
                              void* d_out, int out_size, void* d_ws, size_t ws_size,
                              hipStream_t stream)
{
    const int*   sent  = (const int*)  d_in[0];
    const float* emb   = (const float*)d_in[1];
    const float* wih_f = (const float*)d_in[2];
    const float* whh_f = (const float*)d_in[3];
    const float* bih_f = (const float*)d_in[4];
    const float* bhh_f = (const float*)d_in[5];
    const float* wih_b = (const float*)d_in[6];
    const float* whh_b = (const float*)d_in[7];
    const float* bih_b = (const float*)d_in[8];
    const float* bhh_b = (const float*)d_in[9];
    const float* wtag  = (const float*)d_in[10];
    const float* btag  = (const float*)d_in[11];
    const float* trans = (const float*)d_in[12];
    float* out = (float*)d_out;

    char* ws = (char*)d_ws;
    size_t off = 0;
    float* xg_f = (float*)(ws + off); off += (size_t)LL * G4H * 4;
    float* xg_b = (float*)(ws + off); off += (size_t)LL * G4H * 4;
    float* hs_f = (float*)(ws + off); off += (size_t)LL * HH * 4;
    float* hs_b = (float*)(ws + off); off += (size_t)LL * HH * 4;
    float* feats= (float*)(ws + off); off += (size_t)LL * 12 * 4;
    u64* comm   = (u64*)(ws + off);   off += 2 * 2 * HH * 8;
    float* Pmat = (float*)(ws + off); off += (size_t)64 * TT * TT * 4;
    float* fvb  = (float*)(ws + off); off += (size_t)65 * TT * 4 + 64;
    u64* bpw    = (u64*)(ws + off);   off += (size_t)LL * 8;

    if (off > ws_size){
        k_dbg<<<1, 1, 0, stream>>>(out, (float)ws_size);
        return;
    }

    k0_zero<<<8, 256, 0, stream>>>(comm);
    k1_xg<<<dim3(128, 8, 2), 256, 0, stream>>>(sent, emb, wih_f, bih_f, bhh_f,
                                               wih_b, bih_b, bhh_b, xg_f, xg_b);
    k2_lstm<<<64, 512, 0, stream>>>(whh_f, whh_b, xg_f, xg_b, hs_f, hs_b, comm);
    k3_feats<<<LL, 64, 0, stream>>>(hs_f, hs_b, wtag, btag, feats);
    k4a_chunk<<<64, 64, 0, stream>>>(feats, trans, Pmat);
    k4b_bound<<<1, 64, 0, stream>>>(Pmat, fvb);
    k4c_bp<<<64, 64, 0, stream>>>(feats, trans, fvb, bpw);
    k4d_bt<<<1, 256, 0, stream>>>(bpw, fvb, trans, out);
}